// Round 7
// baseline (369.066 us; speedup 1.0000x reference)
//
#include <hip/hip_runtime.h>
#include <hip/hip_bf16.h>
#include <cstdint>

#define NC 28
#define HW 65536   // 256*256
#define ROWW 256
#define COLW 310
#define BATCH 16
#define TPW 264                    // padded t row width (words); interior at [4..259]
#define TPLANE (256 * TPW)         // words per padded t plane

typedef __hip_bfloat16 bf16;

__device__ __forceinline__ float bflo(unsigned int u) { return __uint_as_float(u << 16); }
__device__ __forceinline__ float bfhi(unsigned int u) { return __uint_as_float(u & 0xffff0000u); }
__device__ __forceinline__ float sgpr(float x) {
    return __int_as_float(__builtin_amdgcn_readfirstlane(__float_as_int(x)));
}
__device__ __forceinline__ unsigned int pk2(float lo, float hi) {
    unsigned short l = __builtin_bit_cast(unsigned short, __float2bfloat16(lo));
    unsigned short h = __builtin_bit_cast(unsigned short, __float2bfloat16(hi));
    return (unsigned int)l | ((unsigned int)h << 16);
}
__device__ __forceinline__ float2 upk(unsigned int u) {
    return make_float2(__uint_as_float(u << 16), __uint_as_float(u & 0xffff0000u));
}
// packed 2xf32 fma: acc = w*x + acc  (one VALU inst for both branches; w in SGPR pair)
__device__ __forceinline__ void pkfma(float2& acc, const float2& w, const float2& x) {
    asm("v_pk_fma_f32 %0, %1, %2, %0" : "+v"(acc) : "s"(w), "v"(x));
}

#define REP28(X) X(0) X(1) X(2) X(3) X(4) X(5) X(6) X(7) X(8) X(9) X(10) X(11) X(12) X(13) \
                 X(14) X(15) X(16) X(17) X(18) X(19) X(20) X(21) X(22) X(23) X(24) X(25) X(26) X(27)

// hdr layout (floats):
//   [0 .. 1567] w1pair[c][o]; [1568 .. 3135] w2pair[o][m];
//   [3136 .. 3191] b1pair[o]; [3192 .. 3247] b2pair[o]; [3248 .. 3557] alpha[col]
#define HDR_BYTES 16384

// ---------------- K0: prep — interleave weight pairs, compute alpha ----------------
__global__ void k0_prep(const float* __restrict__ w1mm, const float* __restrict__ w1pv,
                        const float* __restrict__ w2mm, const float* __restrict__ w2pv,
                        const float* __restrict__ b1mm, const float* __restrict__ b1pv,
                        const float* __restrict__ b2mm, const float* __restrict__ b2pv,
                        float* __restrict__ hdr)
{
    int t = threadIdx.x;
    for (int e = t; e < 784; e += 256) {
        int c = e / 28, o = e - c * 28;
        hdr[2 * e]     = w1mm[o * 28 + c];
        hdr[2 * e + 1] = w1pv[o * 28 + c];
        hdr[1568 + 2 * e]     = w2mm[e];
        hdr[1568 + 2 * e + 1] = w2pv[e];
    }
    if (t < 28) {
        hdr[3136 + 2 * t]     = b1mm[t];
        hdr[3136 + 2 * t + 1] = b1pv[t];
        hdr[3192 + 2 * t]     = b2mm[t];
        hdr[3192 + 2 * t + 1] = b2pv[t];
    }
    for (int col = t; col < COLW; col += 256) {
        int imin = (col > 255) ? ((col - 254) >> 1) : 0;
        int imax = min(27, col >> 1);
        hdr[3248 + col] = 1.0f / (float)(imax - imin + 1);
    }
}

// ---------------- Kpad: zero the pad columns of the padded t buffer ----------------
__global__ void kpad(unsigned int* __restrict__ t_pad)
{
    int idx = blockIdx.x * 256 + threadIdx.x;   // 2 * 448*256 = 229376 exact
    int row = idx >> 1;
    int side = idx & 1;
    uint4* p = (uint4*)(t_pad + (size_t)row * TPW + (side ? 260 : 0));
    *p = make_uint4(0u, 0u, 0u, 0u);
}

// ---------------- K1: conv1x1 x2 both branches; 2 pixels/thread, named accumulators ----------------
__global__ __launch_bounds__(256, 3) void k1_conv1x1(
    const float* __restrict__ Phi, const float* __restrict__ hdr,
    unsigned int* __restrict__ t_pad, unsigned int* __restrict__ m1_pk)
{
    int idx = blockIdx.x * 256 + threadIdx.x;   // 0 .. 524287 (pixel pairs)
    int b   = idx >> 15;                        // HW/2 = 32768 pairs per batch
    int hw2 = (idx & 32767) << 1;               // even pixel index
    const float*  phi = Phi + (size_t)b * NC * HW + hw2;
    const float2* w1p = (const float2*)hdr;             // [c*28+o]
    const float2* w2p = (const float2*)(hdr + 1568);    // [o*28+m]
    const float2* b1p = (const float2*)(hdr + 3136);
    const float2* b2p = (const float2*)(hdr + 3192);

    // 56 named packed accumulators: A = pixel0, B = pixel1; (.x=mm, .y=pv)
#define DECL_M(i) float2 MA##i = b1p[i]; float2 MB##i = MA##i;
    REP28(DECL_M)
#undef DECL_M

    for (int c = 0; c < NC; c++) {
        float2 P = *reinterpret_cast<const float2*>(phi + (size_t)c * HW);
        float2 Pa = make_float2(P.x, P.x);
        float2 Pb = make_float2(P.y, P.y);
        const float2* wr = w1p + c * NC;
#define FMA_M(i) pkfma(MA##i, wr[i], Pa); pkfma(MB##i, wr[i], Pb);
        REP28(FMA_M)
#undef FMA_M
    }

    size_t mbase = (size_t)b * NC * HW + hw2;
#define ST_M(i) *reinterpret_cast<uint2*>(m1_pk + mbase + (size_t)(i) * HW) = \
    make_uint2(pk2(MA##i.x, MA##i.y), pk2(MB##i.x, MB##i.y));
    REP28(ST_M)
#undef ST_M

    int h = hw2 >> 8, wcol = hw2 & 255;
    size_t tbase = ((size_t)(b * NC) * 256 + h) * TPW + 4 + wcol;
    for (int o = 0; o < NC; o++) {
        const float2* wr = w2p + o * NC;
        float2 Ta = b2p[o];
        float2 Tb = Ta;
#define FMA_T(i) pkfma(Ta, wr[i], MA##i); pkfma(Tb, wr[i], MB##i);
        REP28(FMA_T)
#undef FMA_T
        *reinterpret_cast<uint2*>(t_pad + tbase + (size_t)o * TPLANE) =
            make_uint2(pk2(Ta.x, Ta.y), pk2(Tb.x, Tb.y));
    }
}

// ---------------- K2: dwconv5 + sigmoid + emb + where; NO LDS, rolling window from padded t ----------------
#define TRK2 32

#define LOADR(S, GR) do { \
    int gr_ = (GR); \
    unsigned int u0_=0u, u1_=0u, u2_=0u, u3_=0u, u4_=0u; \
    if (gr_ >= 0 && gr_ < 256) { \
        const unsigned int* rp_ = tpl + (size_t)gr_ * TPW + 2 + w; \
        u0_=rp_[0]; u1_=rp_[1]; u2_=rp_[2]; u3_=rp_[3]; u4_=rp_[4]; \
    } \
    W##S##0 = upk(u0_); W##S##1 = upk(u1_); W##S##2 = upk(u2_); \
    W##S##3 = upk(u3_); W##S##4 = upk(u4_); \
} while(0)

#define TAP5(S, B) \
    pkfma(acc, wq[(B)+0], W##S##0); \
    pkfma(acc, wq[(B)+1], W##S##1); \
    pkfma(acc, wq[(B)+2], W##S##2); \
    pkfma(acc, wq[(B)+3], W##S##3); \
    pkfma(acc, wq[(B)+4], W##S##4);

#define CROW(R, S0,S1,S2,S3,S4) do { \
    size_t off_ = cbase + (size_t)(r0 + (R)) * 256 + w; \
    unsigned int mu_ = m1_pk[off_]; \
    float xp_ = x_pre[off_]; \
    float2 acc = make_float2(dbmc, dbpc); \
    TAP5(S0, 0) TAP5(S1, 5) TAP5(S2, 10) TAP5(S3, 15) TAP5(S4, 20) \
    float attm = __builtin_amdgcn_rcpf(1.f + __expf(-acc.x)); \
    float attp = __builtin_amdgcn_rcpf(1.f + __expf(-acc.y)); \
    float m1m_ = bflo(mu_), m1p_ = bfhi(mu_); \
    float embm_ = fmaf(m1m_, attm, m1m_); \
    float embp_ = fmaf(m1p_, attp, m1p_); \
    if (embm_ == 0.f) embm_ = 1e-6f; \
    if (embp_ == 0.f) embp_ = 1e-6f; \
    z[off_]      = __float2bfloat16(xp_ * embm_); \
    philpv[off_] = __float2bfloat16(embp_); \
} while(0)

#define GROUP5(Rb) \
    LOADR(4, r0+(Rb)+2);  CROW((Rb)+0, 0,1,2,3,4); \
    LOADR(0, r0+(Rb)+3);  CROW((Rb)+1, 1,2,3,4,0); \
    LOADR(1, r0+(Rb)+4);  CROW((Rb)+2, 2,3,4,0,1); \
    LOADR(2, r0+(Rb)+5);  CROW((Rb)+3, 3,4,0,1,2); \
    LOADR(3, r0+(Rb)+6);  CROW((Rb)+4, 4,0,1,2,3);

__global__ __launch_bounds__(256, 5) void k2_attn(
    const unsigned int* __restrict__ t_pad, const unsigned int* __restrict__ m1_pk,
    const float* __restrict__ x_pre,
    const float* __restrict__ dwm, const float* __restrict__ dbm,
    const float* __restrict__ dwp, const float* __restrict__ dbp,
    bf16* __restrict__ z, bf16* __restrict__ philpv)
{
    int bid = blockIdx.x;
    int rt = bid & 7;                    // 8 row-tiles of 32
    int c  = (bid >> 3) % NC;
    int b  = (bid >> 3) / NC;
    int r0 = rt * TRK2;
    const unsigned int* tpl = t_pad + (size_t)(b * NC + c) * TPLANE;
    size_t cbase = ((size_t)b * NC + c) * HW;
    int w = threadIdx.x;                 // output column 0..255

    float2 wq[25];
#pragma unroll
    for (int k = 0; k < 25; k++)
        wq[k] = make_float2(sgpr(dwm[c * 25 + k]), sgpr(dwp[c * 25 + k]));
    float dbmc = sgpr(dbm[c]), dbpc = sgpr(dbp[c]);

    float2 W00,W01,W02,W03,W04, W10,W11,W12,W13,W14, W20,W21,W22,W23,W24,
           W30,W31,W32,W33,W34, W40,W41,W42,W43,W44;

    LOADR(0, r0 - 2); LOADR(1, r0 - 1); LOADR(2, r0); LOADR(3, r0 + 1);
    GROUP5(0) GROUP5(5) GROUP5(10) GROUP5(15) GROUP5(20) GROUP5(25)
    LOADR(4, r0 + 32); CROW(30, 0,1,2,3,4);
    LOADR(0, r0 + 33); CROW(31, 1,2,3,4,0);
}

// ---------------- K3: temp = alpha * (y - A_op partial sums) ----------------
__global__ void k3_aop(const float* __restrict__ y, const bf16* __restrict__ z,
                       const float* __restrict__ alpha, float* __restrict__ temp)
{
    int idx = blockIdx.x * 256 + threadIdx.x;
    if (idx >= BATCH * ROWW * COLW) return;
    int col = idx % COLW;
    int bh  = idx / COLW;
    int h = bh & 255;
    int b = bh >> 8;
    int imin = (col > 255) ? ((col - 254) >> 1) : 0;
    int imax = min(27, col >> 1);
    float acc = y[idx];
    size_t base = (size_t)b * NC * HW + (size_t)h * 256 + col;
    for (int i = imin; i <= imax; i++) {
        acc -= __bfloat162float(z[base + (size_t)i * (HW - 2)]);
    }
    temp[idx] = acc * alpha[col];
}

// ---------------- K4: out = x_pre + delta * temp_gathered * PhiL_pv (x4 vectorized) ----------------
__global__ void k4_out(const float* __restrict__ x_pre, const bf16* __restrict__ philpv,
                       const float* __restrict__ temp, const float* __restrict__ delta,
                       float* __restrict__ out)
{
    int idx4 = blockIdx.x * 256 + threadIdx.x;   // quad index; exact grid
    int wq4 = idx4 & 63;
    int rest = idx4 >> 6;
    int h = rest & 255; rest >>= 8;
    int i = rest % NC;
    int b = rest / NC;
    int w = wq4 * 4;
    int col = w + 2 * i;
    const float* trow = temp + ((size_t)(b * 256 + h)) * COLW + col;
    float t0 = trow[0], t1 = trow[1], t2 = trow[2], t3 = trow[3];
    size_t off = ((size_t)(b * NC + i)) * HW + (size_t)(h * 256 + w);
    uint2 pu = *reinterpret_cast<const uint2*>(philpv + off);
    float4 xp = *reinterpret_cast<const float4*>(x_pre + off);
    float d = delta[0];
    float4 o4;
    o4.x = fmaf(d * t0, bflo(pu.x), xp.x);
    o4.y = fmaf(d * t1, bfhi(pu.x), xp.y);
    o4.z = fmaf(d * t2, bflo(pu.y), xp.z);
    o4.w = fmaf(d * t3, bfhi(pu.y), xp.w);
    *reinterpret_cast<float4*>(out + off) = o4;
}

// ---------------- launch ----------------
extern "C" void kernel_launch(void* const* d_in, const int* in_sizes, int n_in,
                              void* d_out, int out_size, void* d_ws, size_t ws_size,
                              hipStream_t stream)
{
    const float* y     = (const float*)d_in[0];
    const float* Phi   = (const float*)d_in[1];
    const float* x_pre = (const float*)d_in[2];
    const float* delta = (const float*)d_in[3];
    const float* mm_w1 = (const float*)d_in[4];
    const float* mm_b1 = (const float*)d_in[5];
    const float* mm_w2 = (const float*)d_in[6];
    const float* mm_b2 = (const float*)d_in[7];
    const float* mm_dw = (const float*)d_in[8];
    const float* mm_db = (const float*)d_in[9];
    const float* pv_w1 = (const float*)d_in[10];
    const float* pv_b1 = (const float*)d_in[11];
    const float* pv_w2 = (const float*)d_in[12];
    const float* pv_b2 = (const float*)d_in[13];
    const float* pv_dw = (const float*)d_in[14];
    const float* pv_db = (const float*)d_in[15];
    float* out = (float*)d_out;

    char* ws = (char*)d_ws;
    const size_t TPAD_BYTES = (size_t)BATCH * NC * TPLANE * 4;   // 121,110,528
    const size_t A = (size_t)BATCH * NC * HW * 4;                // 117,440,512
    float*        hdr    = (float*)ws;
    unsigned int* t_pad  = (unsigned int*)(ws + HDR_BYTES);
    unsigned int* m1_pk  = (unsigned int*)(ws + HDR_BYTES + TPAD_BYTES);
    bf16*         zz     = (bf16*)(ws + HDR_BYTES + TPAD_BYTES + A);
    bf16*         philpv = (bf16*)(ws + HDR_BYTES + TPAD_BYTES + A + A / 2);
    float*        temp   = (float*)(ws + HDR_BYTES + TPAD_BYTES + 2 * A);

    k0_prep<<<1, 256, 0, stream>>>(mm_w1, pv_w1, mm_w2, pv_w2,
                                   mm_b1, pv_b1, mm_b2, pv_b2, hdr);
    kpad<<<(2 * BATCH * NC * 256) / 256, 256, 0, stream>>>(t_pad);
    k1_conv1x1<<<2048, 256, 0, stream>>>(Phi, hdr, t_pad, m1_pk);
    k2_attn<<<BATCH * NC * 8, 256, 0, stream>>>(t_pad, m1_pk, x_pre,
                                                mm_dw, mm_db, pv_dw, pv_db, zz, philpv);
    k3_aop<<<(BATCH * ROWW * COLW + 255) / 256, 256, 0, stream>>>(y, zz, hdr + 3248, temp);
    k4_out<<<(BATCH * NC * HW / 4) / 256, 256, 0, stream>>>(x_pre, philpv, temp, delta, out);
}

// Round 8
// 295.297 us; speedup vs baseline: 1.2498x; 1.2498x over previous
//
#include <hip/hip_runtime.h>
#include <hip/hip_bf16.h>
#include <cstdint>

#define NC 28
#define HW 65536   // 256*256
#define ROWW 256
#define COLW 310
#define BATCH 16

typedef __hip_bfloat16 bf16;

__device__ __forceinline__ float bflo(unsigned int u) { return __uint_as_float(u << 16); }
__device__ __forceinline__ float bfhi(unsigned int u) { return __uint_as_float(u & 0xffff0000u); }
__device__ __forceinline__ float sgpr(float x) {
    return __int_as_float(__builtin_amdgcn_readfirstlane(__float_as_int(x)));
}
__device__ __forceinline__ unsigned int pk2(float lo, float hi) {
    unsigned short l = __builtin_bit_cast(unsigned short, __float2bfloat16(lo));
    unsigned short h = __builtin_bit_cast(unsigned short, __float2bfloat16(hi));
    return (unsigned int)l | ((unsigned int)h << 16);
}
__device__ __forceinline__ float2 upk(unsigned int u) {
    return make_float2(__uint_as_float(u << 16), __uint_as_float(u & 0xffff0000u));
}
// packed 2xf32 fma: acc = w*x + acc  (one VALU inst for both branches; w in SGPR pair)
__device__ __forceinline__ void pkfma(float2& acc, const float2& w, const float2& x) {
    asm("v_pk_fma_f32 %0, %1, %2, %0" : "+v"(acc) : "s"(w), "v"(x));
}

#define REP28A(X) X(0) X(1) X(2) X(3) X(4) X(5) X(6) X(7) X(8) X(9) X(10) X(11) X(12) X(13) \
                  X(14) X(15) X(16) X(17) X(18) X(19) X(20) X(21) X(22) X(23) X(24) X(25) X(26) X(27)
#define REP28B(X) X(0) X(1) X(2) X(3) X(4) X(5) X(6) X(7) X(8) X(9) X(10) X(11) X(12) X(13) \
                  X(14) X(15) X(16) X(17) X(18) X(19) X(20) X(21) X(22) X(23) X(24) X(25) X(26) X(27)

// hdr layout (floats):
//   [0 .. 1567] w1pair[c][o]; [1568 .. 3135] w2pair[o][m];
//   [3136 .. 3191] b1pair[o]; [3192 .. 3247] b2pair[o]; [3248 .. 3557] alpha[col]
#define HDR_BYTES 16384

// ---------------- K0: prep — interleave weight pairs, compute alpha ----------------
__global__ void k0_prep(const float* __restrict__ w1mm, const float* __restrict__ w1pv,
                        const float* __restrict__ w2mm, const float* __restrict__ w2pv,
                        const float* __restrict__ b1mm, const float* __restrict__ b1pv,
                        const float* __restrict__ b2mm, const float* __restrict__ b2pv,
                        float* __restrict__ hdr)
{
    int t = threadIdx.x;
    for (int e = t; e < 784; e += 256) {
        int c = e / 28, o = e - c * 28;
        hdr[2 * e]     = w1mm[o * 28 + c];
        hdr[2 * e + 1] = w1pv[o * 28 + c];
        hdr[1568 + 2 * e]     = w2mm[e];
        hdr[1568 + 2 * e + 1] = w2pv[e];
    }
    if (t < 28) {
        hdr[3136 + 2 * t]     = b1mm[t];
        hdr[3136 + 2 * t + 1] = b1pv[t];
        hdr[3192 + 2 * t]     = b2mm[t];
        hdr[3192 + 2 * t + 1] = b2pv[t];
    }
    for (int col = t; col < COLW; col += 256) {
        int imin = (col > 255) ? ((col - 254) >> 1) : 0;
        int imax = min(27, col >> 1);
        hdr[3248 + col] = 1.0f / (float)(imax - imin + 1);
    }
}

// ---------------- K1: conv1x1 x2 both branches; preloaded Phi, named accumulators ----------------
__global__ __launch_bounds__(256, 4) void k1_conv1x1(
    const float* __restrict__ Phi, const float* __restrict__ hdr,
    unsigned int* __restrict__ t_pk, unsigned int* __restrict__ m1_pk)
{
    int idx = blockIdx.x * 256 + threadIdx.x;   // 0 .. 1048575
    int b  = idx >> 16;                          // HW = 2^16
    int hw = idx & (HW - 1);
    const float*  phi = Phi + (size_t)b * NC * HW + hw;
    const float2* w1p = (const float2*)hdr;             // [c*28+o]
    const float2* w2p = (const float2*)(hdr + 1568);    // [o*28+m]
    const float2* b1p = (const float2*)(hdr + 3136);
    const float2* b2p = (const float2*)(hdr + 3192);

    // preload all 28 Phi values (independent loads, issued before the FMA storm)
#define DECL_P(i) float P##i = phi[(size_t)(i) * HW];
    REP28A(DECL_P)
#undef DECL_P

    // 28 named packed accumulators (.x=mm, .y=pv)
#define DECL_M(i) float2 M##i = b1p[i];
    REP28A(DECL_M)
#undef DECL_M

    // stage 1: fully unrolled over c (named P regs, named M accumulators)
#define FMA_M1(i) pkfma(M##i, wr1_[i], pp_);
#define S1C(c) { float2 pp_ = make_float2(P##c, P##c); \
                 const float2* wr1_ = w1p + (c) * NC; \
                 REP28A(FMA_M1) }
    REP28B(S1C)
#undef S1C
#undef FMA_M1

    size_t base = (size_t)b * NC * HW + hw;
#define ST_M(i) m1_pk[base + (size_t)(i) * HW] = pk2(M##i.x, M##i.y);
    REP28A(ST_M)
#undef ST_M

    // stage 2: one named accumulator per output, stored immediately
    for (int o = 0; o < NC; o++) {
        const float2* wr2_ = w2p + o * NC;
        float2 T = b2p[o];
#define FMA_T(i) pkfma(T, wr2_[i], M##i);
        REP28A(FMA_T)
#undef FMA_T
        t_pk[base + (size_t)o * HW] = pk2(T.x, T.y);
    }
}

// ---------------- K2: dwconv5 + sigmoid + emb + where; LDS staging + rotating prefetch ----------------
#define TR 16
#define LROW 264   // words per LDS row; interior at [4..259], pads [2,3] and [260,261]; 16B-aligned

#define LDROW(S, LR) do { \
    const unsigned int* rp_ = &st[(LR) * LROW + 2 + w]; \
    unsigned int u0_=rp_[0], u1_=rp_[1], u2_=rp_[2], u3_=rp_[3], u4_=rp_[4]; \
    W##S##0 = upk(u0_); W##S##1 = upk(u1_); W##S##2 = upk(u2_); \
    W##S##3 = upk(u3_); W##S##4 = upk(u4_); \
} while(0)

// prefetch m1 / x_pre for tile row R into named slot S (4-row lead)
#define PRE(S, R) do { \
    size_t o_ = cbase + (size_t)(r0 + (R)) * 256 + w; \
    mu##S = m1_pk[o_]; \
    xp##S = x_pre[o_]; \
} while(0)

#define TAP5(S, B) \
    pkfma(acc, wq[(B)+0], W##S##0); \
    pkfma(acc, wq[(B)+1], W##S##1); \
    pkfma(acc, wq[(B)+2], W##S##2); \
    pkfma(acc, wq[(B)+3], W##S##3); \
    pkfma(acc, wq[(B)+4], W##S##4);

#define CROW(R, PS, S0,S1,S2,S3,S4) do { \
    float2 acc = make_float2(dbmc, dbpc); \
    TAP5(S0, 0) TAP5(S1, 5) TAP5(S2, 10) TAP5(S3, 15) TAP5(S4, 20) \
    float attm = __builtin_amdgcn_rcpf(1.f + __expf(-acc.x)); \
    float attp = __builtin_amdgcn_rcpf(1.f + __expf(-acc.y)); \
    float m1m_ = bflo(mu##PS), m1p_ = bfhi(mu##PS); \
    float embm_ = fmaf(m1m_, attm, m1m_); \
    float embp_ = fmaf(m1p_, attp, m1p_); \
    if (embm_ == 0.f) embm_ = 1e-6f; \
    if (embp_ == 0.f) embp_ = 1e-6f; \
    size_t off_ = cbase + (size_t)(r0 + (R)) * 256 + w; \
    z[off_]      = __float2bfloat16(xp##PS * embm_); \
    philpv[off_] = __float2bfloat16(embp_); \
} while(0)

__global__ __launch_bounds__(256, 4) void k2_attn(
    const unsigned int* __restrict__ t_pk, const unsigned int* __restrict__ m1_pk,
    const float* __restrict__ x_pre,
    const float* __restrict__ dwm, const float* __restrict__ dbm,
    const float* __restrict__ dwp, const float* __restrict__ dbp,
    bf16* __restrict__ z, bf16* __restrict__ philpv)
{
    __shared__ unsigned int st[(TR + 4) * LROW];   // 20*264*4 = 21,120 B

    int bid = blockIdx.x;
    int rt = bid & 15;
    int c  = (bid >> 4) % NC;
    int b  = (bid >> 4) / NC;
    int r0 = rt * TR;
    size_t cbase = ((size_t)b * NC + c) * HW;
    int tid = threadIdx.x;
    int lane = tid & 63;
    int wv = tid >> 6;
    int w = tid;   // output column 0..255

    if (tid < 80) {
        int rr = tid >> 2, jj = tid & 3;
        st[rr * LROW + ((jj < 2) ? 2 + jj : 258 + jj)] = 0u;
    }

#pragma unroll
    for (int j = 0; j < 5; j++) {
        int r = wv * 5 + j;
        int gr = r0 - 2 + r;
        if (gr >= 0 && gr < 256) {
            const unsigned int* gsrc = t_pk + cbase + (size_t)gr * 256 + lane * 4;
            __builtin_amdgcn_global_load_lds(
                (const __attribute__((address_space(1))) unsigned int*)gsrc,
                (__attribute__((address_space(3))) unsigned int*)&st[r * LROW + 4],
                16, 0, 0);
        } else {
            st[r * LROW + 4 + lane]       = 0u;
            st[r * LROW + 4 + 64 + lane]  = 0u;
            st[r * LROW + 4 + 128 + lane] = 0u;
            st[r * LROW + 4 + 192 + lane] = 0u;
        }
    }

    float2 wq[25];
#pragma unroll
    for (int k = 0; k < 25; k++)
        wq[k] = make_float2(sgpr(dwm[c * 25 + k]), sgpr(dwp[c * 25 + k]));
    float dbmc = sgpr(dbm[c]), dbpc = sgpr(dbp[c]);

    // prefetch rows 0..3 BEFORE the barrier — hidden under the staging drain
    unsigned int mu0, mu1, mu2, mu3, mu4;
    float xp0, xp1, xp2, xp3, xp4;
    PRE(0, 0); PRE(1, 1); PRE(2, 2); PRE(3, 3);

    __syncthreads();

    float2 W00,W01,W02,W03,W04, W10,W11,W12,W13,W14, W20,W21,W22,W23,W24,
           W30,W31,W32,W33,W34, W40,W41,W42,W43,W44;

    LDROW(0,0); LDROW(1,1); LDROW(2,2); LDROW(3,3);
    LDROW(4,4);  PRE(4,4);   CROW(0,  0, 0,1,2,3,4);
    LDROW(0,5);  PRE(0,5);   CROW(1,  1, 1,2,3,4,0);
    LDROW(1,6);  PRE(1,6);   CROW(2,  2, 2,3,4,0,1);
    LDROW(2,7);  PRE(2,7);   CROW(3,  3, 3,4,0,1,2);
    LDROW(3,8);  PRE(3,8);   CROW(4,  4, 4,0,1,2,3);
    LDROW(4,9);  PRE(4,9);   CROW(5,  0, 0,1,2,3,4);
    LDROW(0,10); PRE(0,10);  CROW(6,  1, 1,2,3,4,0);
    LDROW(1,11); PRE(1,11);  CROW(7,  2, 2,3,4,0,1);
    LDROW(2,12); PRE(2,12);  CROW(8,  3, 3,4,0,1,2);
    LDROW(3,13); PRE(3,13);  CROW(9,  4, 4,0,1,2,3);
    LDROW(4,14); PRE(4,14);  CROW(10, 0, 0,1,2,3,4);
    LDROW(0,15); PRE(0,15);  CROW(11, 1, 1,2,3,4,0);
    LDROW(1,16);             CROW(12, 2, 2,3,4,0,1);
    LDROW(2,17);             CROW(13, 3, 3,4,0,1,2);
    LDROW(3,18);             CROW(14, 4, 4,0,1,2,3);
    LDROW(4,19);             CROW(15, 0, 0,1,2,3,4);
}

// ---------------- K3: temp = alpha * (y - A_op partial sums) ----------------
__global__ void k3_aop(const float* __restrict__ y, const bf16* __restrict__ z,
                       const float* __restrict__ alpha, float* __restrict__ temp)
{
    int idx = blockIdx.x * 256 + threadIdx.x;
    if (idx >= BATCH * ROWW * COLW) return;
    int col = idx % COLW;
    int bh  = idx / COLW;
    int h = bh & 255;
    int b = bh >> 8;
    int imin = (col > 255) ? ((col - 254) >> 1) : 0;
    int imax = min(27, col >> 1);
    float acc = y[idx];
    size_t base = (size_t)b * NC * HW + (size_t)h * 256 + col;
    for (int i = imin; i <= imax; i++) {
        acc -= __bfloat162float(z[base + (size_t)i * (HW - 2)]);
    }
    temp[idx] = acc * alpha[col];
}

// ---------------- K4: out = x_pre + delta * temp_gathered * PhiL_pv (x4 vectorized) ----------------
__global__ void k4_out(const float* __restrict__ x_pre, const bf16* __restrict__ philpv,
                       const float* __restrict__ temp, const float* __restrict__ delta,
                       float* __restrict__ out)
{
    int idx4 = blockIdx.x * 256 + threadIdx.x;   // quad index; exact grid
    int wq4 = idx4 & 63;
    int rest = idx4 >> 6;
    int h = rest & 255; rest >>= 8;
    int i = rest % NC;
    int b = rest / NC;
    int w = wq4 * 4;
    int col = w + 2 * i;
    const float* trow = temp + ((size_t)(b * 256 + h)) * COLW + col;
    float t0 = trow[0], t1 = trow[1], t2 = trow[2], t3 = trow[3];
    size_t off = ((size_t)(b * NC + i)) * HW + (size_t)(h * 256 + w);
    uint2 pu = *reinterpret_cast<const uint2*>(philpv + off);
    float4 xp = *reinterpret_cast<const float4*>(x_pre + off);
    float d = delta[0];
    float4 o4;
    o4.x = fmaf(d * t0, bflo(pu.x), xp.x);
    o4.y = fmaf(d * t1, bfhi(pu.x), xp.y);
    o4.z = fmaf(d * t2, bflo(pu.y), xp.z);
    o4.w = fmaf(d * t3, bfhi(pu.y), xp.w);
    *reinterpret_cast<float4*>(out + off) = o4;
}

// ---------------- launch ----------------
extern "C" void kernel_launch(void* const* d_in, const int* in_sizes, int n_in,
                              void* d_out, int out_size, void* d_ws, size_t ws_size,
                              hipStream_t stream)
{
    const float* y     = (const float*)d_in[0];
    const float* Phi   = (const float*)d_in[1];
    const float* x_pre = (const float*)d_in[2];
    const float* delta = (const float*)d_in[3];
    const float* mm_w1 = (const float*)d_in[4];
    const float* mm_b1 = (const float*)d_in[5];
    const float* mm_w2 = (const float*)d_in[6];
    const float* mm_b2 = (const float*)d_in[7];
    const float* mm_dw = (const float*)d_in[8];
    const float* mm_db = (const float*)d_in[9];
    const float* pv_w1 = (const float*)d_in[10];
    const float* pv_b1 = (const float*)d_in[11];
    const float* pv_w2 = (const float*)d_in[12];
    const float* pv_b2 = (const float*)d_in[13];
    const float* pv_dw = (const float*)d_in[14];
    const float* pv_db = (const float*)d_in[15];
    float* out = (float*)d_out;

    char* ws = (char*)d_ws;
    const size_t A = (size_t)BATCH * NC * HW * 4;   // 117,440,512 B
    float*        hdr    = (float*)ws;
    unsigned int* t_pk   = (unsigned int*)(ws + HDR_BYTES);
    unsigned int* m1_pk  = (unsigned int*)(ws + HDR_BYTES + A);
    bf16*         zz     = (bf16*)(ws + HDR_BYTES + 2 * A);
    bf16*         philpv = (bf16*)(ws + HDR_BYTES + 2 * A + A / 2);
    float*        temp   = (float*)(ws + HDR_BYTES + 3 * A);

    k0_prep<<<1, 256, 0, stream>>>(mm_w1, pv_w1, mm_w2, pv_w2,
                                   mm_b1, pv_b1, mm_b2, pv_b2, hdr);
    k1_conv1x1<<<4096, 256, 0, stream>>>(Phi, hdr, t_pk, m1_pk);
    k2_attn<<<BATCH * NC * 16, 256, 0, stream>>>(t_pk, m1_pk, x_pre,
                                                 mm_dw, mm_db, pv_dw, pv_db, zz, philpv);
    k3_aop<<<(BATCH * ROWW * COLW + 255) / 256, 256, 0, stream>>>(y, zz, hdr + 3248, temp);
    k4_out<<<(BATCH * NC * HW / 4) / 256, 256, 0, stream>>>(x_pre, philpv, temp, delta, out);
}

// Round 10
// 281.600 us; speedup vs baseline: 1.3106x; 1.0486x over previous
//
#include <hip/hip_runtime.h>
#include <hip/hip_bf16.h>
#include <cstdint>

#define NC 28
#define HW 65536   // 256*256
#define ROWW 256
#define COLW 310
#define BATCH 16

typedef __hip_bfloat16 bf16;

__device__ __forceinline__ float bflo(unsigned int u) { return __uint_as_float(u << 16); }
__device__ __forceinline__ float bfhi(unsigned int u) { return __uint_as_float(u & 0xffff0000u); }
__device__ __forceinline__ unsigned int pk2(float lo, float hi) {
    unsigned short l = __builtin_bit_cast(unsigned short, __float2bfloat16(lo));
    unsigned short h = __builtin_bit_cast(unsigned short, __float2bfloat16(hi));
    return (unsigned int)l | ((unsigned int)h << 16);
}
// pack two f32 -> two f16 in one uint (v_cvt_pkrtz_f16_f32)
__device__ __forceinline__ unsigned int pkh(float lo, float hi) {
    auto h = __builtin_amdgcn_cvt_pkrtz(lo, hi);
    return __builtin_bit_cast(unsigned int, h);
}
__device__ __forceinline__ float h2f_lo(unsigned int u) {
    return (float)__builtin_bit_cast(_Float16, (unsigned short)(u & 0xffffu));
}
__device__ __forceinline__ float h2f_hi(unsigned int u) {
    return (float)__builtin_bit_cast(_Float16, (unsigned short)(u >> 16));
}
// packed 2xf16 fma: acc = w*x + acc (one full-rate VALU inst; w in one SGPR)
__device__ __forceinline__ void pkfma16(unsigned int& acc, unsigned int w, unsigned int x) {
    asm("v_pk_fma_f16 %0, %1, %2, %0" : "+v"(acc) : "s"(w), "v"(x));
}

#define REP28A(X) X(0) X(1) X(2) X(3) X(4) X(5) X(6) X(7) X(8) X(9) X(10) X(11) X(12) X(13) \
                  X(14) X(15) X(16) X(17) X(18) X(19) X(20) X(21) X(22) X(23) X(24) X(25) X(26) X(27)

// hdr layout (uint words):
//   [0..783]     w1h[c*28+o]  f16 pair (mm,pv)
//   [784..1567]  w2h[o*28+m]
//   [1568..1595] b1h[o]
//   [1596..1623] b2h[o]
//   [1624..2323] dwh[c*25+k]
//   [2324..2351] dbh[c]
//   [2352..2661] alpha[col] (float bits)
#define HDR_BYTES 16384

// ---------------- K0: prep — pack all weights/biases to f16 pairs, compute alpha ----------------
__global__ void k0_prep(const float* __restrict__ w1mm, const float* __restrict__ w1pv,
                        const float* __restrict__ w2mm, const float* __restrict__ w2pv,
                        const float* __restrict__ b1mm, const float* __restrict__ b1pv,
                        const float* __restrict__ b2mm, const float* __restrict__ b2pv,
                        const float* __restrict__ dwm,  const float* __restrict__ dwp,
                        const float* __restrict__ dbm,  const float* __restrict__ dbp,
                        unsigned int* __restrict__ hdr)
{
    int t = threadIdx.x;
    for (int e = t; e < 784; e += 256) {
        int c = e / 28, o = e - c * 28;
        hdr[e]       = pkh(w1mm[o * 28 + c], w1pv[o * 28 + c]);   // transposed
        hdr[784 + e] = pkh(w2mm[e], w2pv[e]);
    }
    if (t < 28) {
        hdr[1568 + t] = pkh(b1mm[t], b1pv[t]);
        hdr[1596 + t] = pkh(b2mm[t], b2pv[t]);
        hdr[2324 + t] = pkh(dbm[t], dbp[t]);
    }
    for (int e = t; e < 700; e += 256)
        hdr[1624 + e] = pkh(dwm[e], dwp[e]);
    float* alpha = (float*)(hdr + 2352);
    for (int col = t; col < COLW; col += 256) {
        int imin = (col > 255) ? ((col - 254) >> 1) : 0;
        int imax = min(27, col >> 1);
        alpha[col] = 1.0f / (float)(imax - imin + 1);
    }
}

// ---------------- K1: conv1x1 x2 both branches; f16 packed math, 2 px/thread ----------------
__global__ __launch_bounds__(256, 4) void k1_conv1x1(
    const float* __restrict__ Phi, const unsigned int* __restrict__ hdr,
    unsigned int* __restrict__ t_pk, unsigned int* __restrict__ m1_pk)
{
    int idx = blockIdx.x * 256 + threadIdx.x;   // pixel-pair index
    int b   = idx >> 15;                        // 32768 pairs per batch
    int hw2 = (idx & 32767) << 1;
    const float* phi = Phi + (size_t)b * NC * HW + hw2;
    const unsigned int* w1h = hdr;              // [c*28+o]
    const unsigned int* w2h = hdr + 784;        // [o*28+m]
    const unsigned int* b1h = hdr + 1568;
    const unsigned int* b2h = hdr + 1596;

    // 56 named f16-pair accumulators: A = px0, B = px1; (lo=mm, hi=pv)
#define DECL_M(i) unsigned int MA##i = b1h[i]; unsigned int MB##i = MA##i;
    REP28A(DECL_M)
#undef DECL_M

    for (int c = 0; c < NC; c++) {
        float2 P = *reinterpret_cast<const float2*>(phi + (size_t)c * HW);
        unsigned int pa = pkh(P.x, P.x);
        unsigned int pb = pkh(P.y, P.y);
        const unsigned int* wr1_ = w1h + c * NC;
#define FMA_M(i) pkfma16(MA##i, wr1_[i], pa); pkfma16(MB##i, wr1_[i], pb);
        REP28A(FMA_M)
#undef FMA_M
    }

    size_t base = (size_t)b * NC * HW + hw2;
    // store m1 raw (f16 pairs — zero conversion)
#define ST_M(i) *reinterpret_cast<uint2*>(m1_pk + base + (size_t)(i) * HW) = make_uint2(MA##i, MB##i);
    REP28A(ST_M)
#undef ST_M

    for (int o = 0; o < NC; o++) {
        const unsigned int* wr2_ = w2h + o * NC;
        unsigned int Ta = b2h[o], Tb = Ta;
#define FMA_T(i) pkfma16(Ta, wr2_[i], MA##i); pkfma16(Tb, wr2_[i], MB##i);
        REP28A(FMA_T)
#undef FMA_T
        *reinterpret_cast<uint2*>(t_pk + base + (size_t)o * HW) = make_uint2(Ta, Tb);
    }
}

// ---------------- K2: dwconv5 + sigmoid + emb + where; f16 packed taps, LDS staging ----------------
#define TR 16
#define LROW 264   // words per LDS row; interior at [4..259], pads [2,3] and [260,261]

#define LDROW(S, LR) do { \
    const unsigned int* rp_ = &st[(LR) * LROW + 2 + w]; \
    W##S##0 = rp_[0]; W##S##1 = rp_[1]; W##S##2 = rp_[2]; W##S##3 = rp_[3]; W##S##4 = rp_[4]; \
} while(0)

#define PRE(S, R) do { \
    size_t o_ = cbase + (size_t)(r0 + (R)) * 256 + w; \
    mu##S = m1_pk[o_]; \
    xp##S = x_pre[o_]; \
} while(0)

#define TAP5(S, B) \
    pkfma16(acc, wq[(B)+0], W##S##0); \
    pkfma16(acc, wq[(B)+1], W##S##1); \
    pkfma16(acc, wq[(B)+2], W##S##2); \
    pkfma16(acc, wq[(B)+3], W##S##3); \
    pkfma16(acc, wq[(B)+4], W##S##4);

#define CROW(R, PS, S0,S1,S2,S3,S4) do { \
    unsigned int acc = dbc; \
    TAP5(S0, 0) TAP5(S1, 5) TAP5(S2, 10) TAP5(S3, 15) TAP5(S4, 20) \
    float accm = h2f_lo(acc), accp = h2f_hi(acc); \
    float attm = __builtin_amdgcn_rcpf(1.f + __expf(-accm)); \
    float attp = __builtin_amdgcn_rcpf(1.f + __expf(-accp)); \
    float m1m_ = h2f_lo(mu##PS), m1p_ = h2f_hi(mu##PS); \
    float embm_ = fmaf(m1m_, attm, m1m_); \
    float embp_ = fmaf(m1p_, attp, m1p_); \
    if (embm_ == 0.f) embm_ = 1e-6f; \
    if (embp_ == 0.f) embp_ = 1e-6f; \
    size_t off_ = cbase + (size_t)(r0 + (R)) * 256 + w; \
    z[off_]      = __float2bfloat16(xp##PS * embm_); \
    philpv[off_] = __float2bfloat16(embp_); \
} while(0)

__global__ __launch_bounds__(256, 4) void k2_attn(
    const unsigned int* __restrict__ t_pk, const unsigned int* __restrict__ m1_pk,
    const float* __restrict__ x_pre, const unsigned int* __restrict__ hdr,
    bf16* __restrict__ z, bf16* __restrict__ philpv)
{
    __shared__ unsigned int st[(TR + 4) * LROW];   // 21,120 B

    int bid = blockIdx.x;
    int rt = bid & 15;
    int c  = (bid >> 4) % NC;
    int b  = (bid >> 4) / NC;
    int r0 = rt * TR;
    size_t cbase = ((size_t)b * NC + c) * HW;
    int tid = threadIdx.x;
    int lane = tid & 63;
    int wv = tid >> 6;
    int w = tid;   // output column 0..255

    if (tid < 80) {
        int rr = tid >> 2, jj = tid & 3;
        st[rr * LROW + ((jj < 2) ? 2 + jj : 258 + jj)] = 0u;
    }

#pragma unroll
    for (int j = 0; j < 5; j++) {
        int r = wv * 5 + j;
        int gr = r0 - 2 + r;
        if (gr >= 0 && gr < 256) {
            const unsigned int* gsrc = t_pk + cbase + (size_t)gr * 256 + lane * 4;
            __builtin_amdgcn_global_load_lds(
                (const __attribute__((address_space(1))) unsigned int*)gsrc,
                (__attribute__((address_space(3))) unsigned int*)&st[r * LROW + 4],
                16, 0, 0);
        } else {
            st[r * LROW + 4 + lane]       = 0u;
            st[r * LROW + 4 + 64 + lane]  = 0u;
            st[r * LROW + 4 + 128 + lane] = 0u;
            st[r * LROW + 4 + 192 + lane] = 0u;
        }
    }

    // depthwise f16-pair weights -> SGPRs (block-uniform)
    unsigned int wq[25];
#pragma unroll
    for (int k = 0; k < 25; k++)
        wq[k] = __builtin_amdgcn_readfirstlane(hdr[1624 + c * 25 + k]);
    unsigned int dbc = __builtin_amdgcn_readfirstlane(hdr[2324 + c]);

    // prefetch rows 0..3 before the barrier
    unsigned int mu0, mu1, mu2, mu3, mu4;
    float xp0, xp1, xp2, xp3, xp4;
    PRE(0, 0); PRE(1, 1); PRE(2, 2); PRE(3, 3);

    __syncthreads();

    unsigned int W00,W01,W02,W03,W04, W10,W11,W12,W13,W14, W20,W21,W22,W23,W24,
                 W30,W31,W32,W33,W34, W40,W41,W42,W43,W44;

    LDROW(0,0); LDROW(1,1); LDROW(2,2); LDROW(3,3);
    LDROW(4,4);  PRE(4,4);   CROW(0,  0, 0,1,2,3,4);
    LDROW(0,5);  PRE(0,5);   CROW(1,  1, 1,2,3,4,0);
    LDROW(1,6);  PRE(1,6);   CROW(2,  2, 2,3,4,0,1);
    LDROW(2,7);  PRE(2,7);   CROW(3,  3, 3,4,0,1,2);
    LDROW(3,8);  PRE(3,8);   CROW(4,  4, 4,0,1,2,3);
    LDROW(4,9);  PRE(4,9);   CROW(5,  0, 0,1,2,3,4);
    LDROW(0,10); PRE(0,10);  CROW(6,  1, 1,2,3,4,0);
    LDROW(1,11); PRE(1,11);  CROW(7,  2, 2,3,4,0,1);
    LDROW(2,12); PRE(2,12);  CROW(8,  3, 3,4,0,1,2);
    LDROW(3,13); PRE(3,13);  CROW(9,  4, 4,0,1,2,3);
    LDROW(4,14); PRE(4,14);  CROW(10, 0, 0,1,2,3,4);
    LDROW(0,15); PRE(0,15);  CROW(11, 1, 1,2,3,4,0);
    LDROW(1,16);             CROW(12, 2, 2,3,4,0,1);
    LDROW(2,17);             CROW(13, 3, 3,4,0,1,2);
    LDROW(3,18);             CROW(14, 4, 4,0,1,2,3);
    LDROW(4,19);             CROW(15, 0, 0,1,2,3,4);
}

// ---------------- K3: temp = alpha * (y - A_op partial sums) ----------------
__global__ void k3_aop(const float* __restrict__ y, const bf16* __restrict__ z,
                       const float* __restrict__ alpha, float* __restrict__ temp)
{
    int idx = blockIdx.x * 256 + threadIdx.x;
    if (idx >= BATCH * ROWW * COLW) return;
    int col = idx % COLW;
    int bh  = idx / COLW;
    int h = bh & 255;
    int b = bh >> 8;
    int imin = (col > 255) ? ((col - 254) >> 1) : 0;
    int imax = min(27, col >> 1);
    float acc = y[idx];
    size_t base = (size_t)b * NC * HW + (size_t)h * 256 + col;
    for (int i = imin; i <= imax; i++) {
        acc -= __bfloat162float(z[base + (size_t)i * (HW - 2)]);
    }
    temp[idx] = acc * alpha[col];
}

// ---------------- K4: out = x_pre + delta * temp_gathered * PhiL_pv (x4 vectorized) ----------------
__global__ void k4_out(const float* __restrict__ x_pre, const bf16* __restrict__ philpv,
                       const float* __restrict__ temp, const float* __restrict__ delta,
                       float* __restrict__ out)
{
    int idx4 = blockIdx.x * 256 + threadIdx.x;   // quad index; exact grid
    int wq4 = idx4 & 63;
    int rest = idx4 >> 6;
    int h = rest & 255; rest >>= 8;
    int i = rest % NC;
    int b = rest / NC;
    int w = wq4 * 4;
    int col = w + 2 * i;
    const float* trow = temp + ((size_t)(b * 256 + h)) * COLW + col;
    float t0 = trow[0], t1 = trow[1], t2 = trow[2], t3 = trow[3];
    size_t off = ((size_t)(b * NC + i)) * HW + (size_t)(h * 256 + w);
    uint2 pu = *reinterpret_cast<const uint2*>(philpv + off);
    float4 xp = *reinterpret_cast<const float4*>(x_pre + off);
    float d = delta[0];
    float4 o4;
    o4.x = fmaf(d * t0, bflo(pu.x), xp.x);
    o4.y = fmaf(d * t1, bfhi(pu.x), xp.y);
    o4.z = fmaf(d * t2, bflo(pu.y), xp.z);
    o4.w = fmaf(d * t3, bfhi(pu.y), xp.w);
    *reinterpret_cast<float4*>(out + off) = o4;
}

// ---------------- launch ----------------
extern "C" void kernel_launch(void* const* d_in, const int* in_sizes, int n_in,
                              void* d_out, int out_size, void* d_ws, size_t ws_size,
                              hipStream_t stream)
{
    const float* y     = (const float*)d_in[0];
    const float* Phi   = (const float*)d_in[1];
    const float* x_pre = (const float*)d_in[2];
    const float* delta = (const float*)d_in[3];
    const float* mm_w1 = (const float*)d_in[4];
    const float* mm_b1 = (const float*)d_in[5];
    const float* mm_w2 = (const float*)d_in[6];
    const float* mm_b2 = (const float*)d_in[7];
    const float* mm_dw = (const float*)d_in[8];
    const float* mm_db = (const float*)d_in[9];
    const float* pv_w1 = (const float*)d_in[10];
    const float* pv_b1 = (const float*)d_in[11];
    const float* pv_w2 = (const float*)d_in[12];
    const float* pv_b2 = (const float*)d_in[13];
    const float* pv_dw = (const float*)d_in[14];
    const float* pv_db = (const float*)d_in[15];
    float* out = (float*)d_out;

    char* ws = (char*)d_ws;
    const size_t A = (size_t)BATCH * NC * HW * 4;   // 117,440,512 B
    unsigned int* hdr    = (unsigned int*)ws;
    unsigned int* t_pk   = (unsigned int*)(ws + HDR_BYTES);
    unsigned int* m1_pk  = (unsigned int*)(ws + HDR_BYTES + A);
    bf16*         zz     = (bf16*)(ws + HDR_BYTES + 2 * A);
    bf16*         philpv = (bf16*)(ws + HDR_BYTES + 2 * A + A / 2);
    float*        temp   = (float*)(ws + HDR_BYTES + 3 * A);
    const float*  alpha  = (const float*)(ws + 2352 * 4);

    k0_prep<<<1, 256, 0, stream>>>(mm_w1, pv_w1, mm_w2, pv_w2,
                                   mm_b1, pv_b1, mm_b2, pv_b2,
                                   mm_dw, pv_dw, mm_db, pv_db, hdr);
    k1_conv1x1<<<2048, 256, 0, stream>>>(Phi, hdr, t_pk, m1_pk);
    k2_attn<<<BATCH * NC * 16, 256, 0, stream>>>(t_pk, m1_pk, x_pre, hdr, zz, philpv);
    k3_aop<<<(BATCH * ROWW * COLW + 255) / 256, 256, 0, stream>>>(y, zz, alpha, temp);
    k4_out<<<(BATCH * NC * HW / 4) / 256, 256, 0, stream>>>(x_pre, philpv, temp, delta, out);
}

// Round 11
// 274.043 us; speedup vs baseline: 1.3467x; 1.0276x over previous
//
#include <hip/hip_runtime.h>
#include <hip/hip_bf16.h>
#include <cstdint>

#define NC 28
#define HW 65536   // 256*256
#define ROWW 256
#define COLW 310
#define BATCH 16

typedef __hip_bfloat16 bf16;

__device__ __forceinline__ float bflo(unsigned int u) { return __uint_as_float(u << 16); }
__device__ __forceinline__ float bfhi(unsigned int u) { return __uint_as_float(u & 0xffff0000u); }
__device__ __forceinline__ unsigned int pk2(float lo, float hi) {
    unsigned short l = __builtin_bit_cast(unsigned short, __float2bfloat16(lo));
    unsigned short h = __builtin_bit_cast(unsigned short, __float2bfloat16(hi));
    return (unsigned int)l | ((unsigned int)h << 16);
}
// pack two f32 -> two f16 in one uint (v_cvt_pkrtz_f16_f32)
__device__ __forceinline__ unsigned int pkh(float lo, float hi) {
    auto h = __builtin_amdgcn_cvt_pkrtz(lo, hi);
    return __builtin_bit_cast(unsigned int, h);
}
__device__ __forceinline__ float h2f_lo(unsigned int u) {
    return (float)__builtin_bit_cast(_Float16, (unsigned short)(u & 0xffffu));
}
__device__ __forceinline__ float h2f_hi(unsigned int u) {
    return (float)__builtin_bit_cast(_Float16, (unsigned short)(u >> 16));
}
// packed 2xf16 fma: acc = w*x + acc (one full-rate VALU inst; w in one SGPR)
__device__ __forceinline__ void pkfma16(unsigned int& acc, unsigned int w, unsigned int x) {
    asm("v_pk_fma_f16 %0, %1, %2, %0" : "+v"(acc) : "s"(w), "v"(x));
}

#define REP28A(X) X(0) X(1) X(2) X(3) X(4) X(5) X(6) X(7) X(8) X(9) X(10) X(11) X(12) X(13) \
                  X(14) X(15) X(16) X(17) X(18) X(19) X(20) X(21) X(22) X(23) X(24) X(25) X(26) X(27)

// hdr layout (uint words):
//   [0..783]     w1h[c*28+o]  f16 pair (mm,pv)
//   [784..1567]  w2h[o*28+m]
//   [1568..1595] b1h[o]
//   [1596..1623] b2h[o]
//   [1624..2323] dwh[c*25+k]
//   [2324..2351] dbh[c]
//   [2352..2661] alpha[col] (float bits)
#define HDR_BYTES 16384

// ---------------- K0: prep ----------------
__global__ void k0_prep(const float* __restrict__ w1mm, const float* __restrict__ w1pv,
                        const float* __restrict__ w2mm, const float* __restrict__ w2pv,
                        const float* __restrict__ b1mm, const float* __restrict__ b1pv,
                        const float* __restrict__ b2mm, const float* __restrict__ b2pv,
                        const float* __restrict__ dwm,  const float* __restrict__ dwp,
                        const float* __restrict__ dbm,  const float* __restrict__ dbp,
                        unsigned int* __restrict__ hdr)
{
    int t = threadIdx.x;
    for (int e = t; e < 784; e += 256) {
        int c = e / 28, o = e - c * 28;
        hdr[e]       = pkh(w1mm[o * 28 + c], w1pv[o * 28 + c]);   // transposed
        hdr[784 + e] = pkh(w2mm[e], w2pv[e]);
    }
    if (t < 28) {
        hdr[1568 + t] = pkh(b1mm[t], b1pv[t]);
        hdr[1596 + t] = pkh(b2mm[t], b2pv[t]);
        hdr[2324 + t] = pkh(dbm[t], dbp[t]);
    }
    for (int e = t; e < 700; e += 256)
        hdr[1624 + e] = pkh(dwm[e], dwp[e]);
    float* alpha = (float*)(hdr + 2352);
    for (int col = t; col < COLW; col += 256) {
        int imin = (col > 255) ? ((col - 254) >> 1) : 0;
        int imax = min(27, col >> 1);
        alpha[col] = 1.0f / (float)(imax - imin + 1);
    }
}

// ---------------- K1: conv1x1 x2 both branches; f16 packed math, 4 px/thread ----------------
__global__ __launch_bounds__(256, 3) void k1_conv1x1(
    const float* __restrict__ Phi, const unsigned int* __restrict__ hdr,
    unsigned int* __restrict__ t_pk, unsigned int* __restrict__ m1_pk)
{
    int idx = blockIdx.x * 256 + threadIdx.x;   // pixel-quad index
    int b   = idx >> 14;                        // 16384 quads per batch
    int hw4 = (idx & 16383) << 2;
    const float* phi = Phi + (size_t)b * NC * HW + hw4;
    const unsigned int* w1h = hdr;              // [c*28+o]
    const unsigned int* w2h = hdr + 784;        // [o*28+m]
    const unsigned int* b1h = hdr + 1568;
    const unsigned int* b2h = hdr + 1596;

    // 112 named f16-pair accumulators: A..D = px0..3; (lo=mm, hi=pv)
#define DECL_M(i) unsigned int MA##i = b1h[i], MB##i = MA##i, MC##i = MA##i, MD##i = MA##i;
    REP28A(DECL_M)
#undef DECL_M

    for (int c = 0; c < NC; c++) {
        float4 P = *reinterpret_cast<const float4*>(phi + (size_t)c * HW);
        unsigned int pa = pkh(P.x, P.x);
        unsigned int pb = pkh(P.y, P.y);
        unsigned int pc = pkh(P.z, P.z);
        unsigned int pd = pkh(P.w, P.w);
        const unsigned int* wr1_ = w1h + c * NC;
#define FMA_M(i) pkfma16(MA##i, wr1_[i], pa); pkfma16(MB##i, wr1_[i], pb); \
                 pkfma16(MC##i, wr1_[i], pc); pkfma16(MD##i, wr1_[i], pd);
        REP28A(FMA_M)
#undef FMA_M
    }

    size_t base = (size_t)b * NC * HW + hw4;
#define ST_M(i) *reinterpret_cast<uint4*>(m1_pk + base + (size_t)(i) * HW) = \
    make_uint4(MA##i, MB##i, MC##i, MD##i);
    REP28A(ST_M)
#undef ST_M

    for (int o = 0; o < NC; o++) {
        const unsigned int* wr2_ = w2h + o * NC;
        unsigned int Ta = b2h[o], Tb = Ta, Tc = Ta, Td = Ta;
#define FMA_T(i) pkfma16(Ta, wr2_[i], MA##i); pkfma16(Tb, wr2_[i], MB##i); \
                 pkfma16(Tc, wr2_[i], MC##i); pkfma16(Td, wr2_[i], MD##i);
        REP28A(FMA_T)
#undef FMA_T
        *reinterpret_cast<uint4*>(t_pk + base + (size_t)o * HW) = make_uint4(Ta, Tb, Tc, Td);
    }
}

// ---------------- K2: dwconv5 + sigmoid + emb + where; 2 cols x 8 rows per thread ----------------
#define TR 16
#define LROW 264   // words per LDS row; interior at [4..259], pads [2,3] and [260,261]

// load LDS row LR into window slot S: 6 words (cols cc-2 .. cc+3) as 3x b64
#define LDROW(S, LR) do { \
    const uint2* rp_ = reinterpret_cast<const uint2*>(&st[(LR) * LROW + 2 + cc]); \
    uint2 a_ = rp_[0], b_ = rp_[1], c_ = rp_[2]; \
    W##S##0 = a_.x; W##S##1 = a_.y; W##S##2 = b_.x; \
    W##S##3 = b_.y; W##S##4 = c_.x; W##S##5 = c_.y; \
} while(0)

// prefetch m1 / x_pre for half-local row R into slot S
#define PRE(S, R) do { \
    size_t o_ = cbase + (size_t)(h0 + (R)) * 256 + cc; \
    mu##S = *reinterpret_cast<const uint2*>(m1_pk + o_); \
    xp##S = *reinterpret_cast<const float2*>(x_pre + o_); \
} while(0)

// one weight row (5 taps) applied to both columns from slot S
#define TAPR(S, B) \
    pkfma16(acc0, wq[(B)+0], W##S##0); pkfma16(acc1, wq[(B)+0], W##S##1); \
    pkfma16(acc0, wq[(B)+1], W##S##1); pkfma16(acc1, wq[(B)+1], W##S##2); \
    pkfma16(acc0, wq[(B)+2], W##S##2); pkfma16(acc1, wq[(B)+2], W##S##3); \
    pkfma16(acc0, wq[(B)+3], W##S##3); pkfma16(acc1, wq[(B)+3], W##S##4); \
    pkfma16(acc0, wq[(B)+4], W##S##4); pkfma16(acc1, wq[(B)+4], W##S##5);

#define CROW2(R, PS, S0,S1,S2,S3,S4) do { \
    unsigned int acc0 = dbc, acc1 = dbc; \
    TAPR(S0, 0) TAPR(S1, 5) TAPR(S2, 10) TAPR(S3, 15) TAPR(S4, 20) \
    float am0 = h2f_lo(acc0), ap0 = h2f_hi(acc0); \
    float am1 = h2f_lo(acc1), ap1 = h2f_hi(acc1); \
    float atm0 = __builtin_amdgcn_rcpf(1.f + __expf(-am0)); \
    float atp0 = __builtin_amdgcn_rcpf(1.f + __expf(-ap0)); \
    float atm1 = __builtin_amdgcn_rcpf(1.f + __expf(-am1)); \
    float atp1 = __builtin_amdgcn_rcpf(1.f + __expf(-ap1)); \
    float m1m0 = h2f_lo(mu##PS.x), m1p0 = h2f_hi(mu##PS.x); \
    float m1m1 = h2f_lo(mu##PS.y), m1p1 = h2f_hi(mu##PS.y); \
    float em0 = fmaf(m1m0, atm0, m1m0); \
    float ep0 = fmaf(m1p0, atp0, m1p0); \
    float em1 = fmaf(m1m1, atm1, m1m1); \
    float ep1 = fmaf(m1p1, atp1, m1p1); \
    if (em0 == 0.f) em0 = 1e-6f; \
    if (ep0 == 0.f) ep0 = 1e-6f; \
    if (em1 == 0.f) em1 = 1e-6f; \
    if (ep1 == 0.f) ep1 = 1e-6f; \
    size_t off_ = cbase + (size_t)(h0 + (R)) * 256 + cc; \
    *reinterpret_cast<unsigned int*>(z + off_)      = pk2(xp##PS.x * em0, xp##PS.y * em1); \
    *reinterpret_cast<unsigned int*>(philpv + off_) = pk2(ep0, ep1); \
} while(0)

__global__ __launch_bounds__(256, 4) void k2_attn(
    const unsigned int* __restrict__ t_pk, const unsigned int* __restrict__ m1_pk,
    const float* __restrict__ x_pre, const unsigned int* __restrict__ hdr,
    bf16* __restrict__ z, bf16* __restrict__ philpv)
{
    __shared__ unsigned int st[(TR + 4) * LROW];   // 21,120 B

    int bid = blockIdx.x;
    int rt = bid & 15;
    int c  = (bid >> 4) % NC;
    int b  = (bid >> 4) / NC;
    int r0 = rt * TR;
    size_t cbase = ((size_t)b * NC + c) * HW;
    int tid = threadIdx.x;
    int lane = tid & 63;
    int wv = tid >> 6;
    int cc = (tid & 127) * 2;        // column pair base
    int half = tid >> 7;             // 0: rows 0..7, 1: rows 8..15
    int lbase = half * 8;            // LDS-local base row of this half's first window
    int h0 = r0 + lbase;             // global first output row for this thread

    if (tid < 80) {
        int rr = tid >> 2, jj = tid & 3;
        st[rr * LROW + ((jj < 2) ? 2 + jj : 258 + jj)] = 0u;
    }

#pragma unroll
    for (int j = 0; j < 5; j++) {
        int r = wv * 5 + j;
        int gr = r0 - 2 + r;
        if (gr >= 0 && gr < 256) {
            const unsigned int* gsrc = t_pk + cbase + (size_t)gr * 256 + lane * 4;
            __builtin_amdgcn_global_load_lds(
                (const __attribute__((address_space(1))) unsigned int*)gsrc,
                (__attribute__((address_space(3))) unsigned int*)&st[r * LROW + 4],
                16, 0, 0);
        } else {
            st[r * LROW + 4 + lane]       = 0u;
            st[r * LROW + 4 + 64 + lane]  = 0u;
            st[r * LROW + 4 + 128 + lane] = 0u;
            st[r * LROW + 4 + 192 + lane] = 0u;
        }
    }

    // depthwise f16-pair weights -> SGPRs (block-uniform)
    unsigned int wq[25];
#pragma unroll
    for (int k = 0; k < 25; k++)
        wq[k] = __builtin_amdgcn_readfirstlane(hdr[1624 + c * 25 + k]);
    unsigned int dbc = __builtin_amdgcn_readfirstlane(hdr[2324 + c]);

    // prefetch rows 0..3 of this half before the barrier
    uint2  mu0, mu1, mu2, mu3, mu4;
    float2 xp0, xp1, xp2, xp3, xp4;
    PRE(0, 0); PRE(1, 1); PRE(2, 2); PRE(3, 3);

    __syncthreads();

    unsigned int W00,W01,W02,W03,W04,W05, W10,W11,W12,W13,W14,W15,
                 W20,W21,W22,W23,W24,W25, W30,W31,W32,W33,W34,W35,
                 W40,W41,W42,W43,W44,W45;

    LDROW(0, lbase + 0); LDROW(1, lbase + 1); LDROW(2, lbase + 2); LDROW(3, lbase + 3);
    LDROW(4, lbase + 4);  PRE(4, 4);  CROW2(0, 0, 0,1,2,3,4);
    LDROW(0, lbase + 5);  PRE(0, 5);  CROW2(1, 1, 1,2,3,4,0);
    LDROW(1, lbase + 6);  PRE(1, 6);  CROW2(2, 2, 2,3,4,0,1);
    LDROW(2, lbase + 7);  PRE(2, 7);  CROW2(3, 3, 3,4,0,1,2);
    LDROW(3, lbase + 8);              CROW2(4, 4, 4,0,1,2,3);
    LDROW(4, lbase + 9);              CROW2(5, 0, 0,1,2,3,4);
    LDROW(0, lbase + 10);             CROW2(6, 1, 1,2,3,4,0);
    LDROW(1, lbase + 11);             CROW2(7, 2, 2,3,4,0,1);
}

// ---------------- K3: temp = alpha * (y - A_op partial sums) ----------------
__global__ void k3_aop(const float* __restrict__ y, const bf16* __restrict__ z,
                       const float* __restrict__ alpha, float* __restrict__ temp)
{
    int idx = blockIdx.x * 256 + threadIdx.x;
    if (idx >= BATCH * ROWW * COLW) return;
    int col = idx % COLW;
    int bh  = idx / COLW;
    int h = bh & 255;
    int b = bh >> 8;
    int imin = (col > 255) ? ((col - 254) >> 1) : 0;
    int imax = min(27, col >> 1);
    float acc = y[idx];
    size_t base = (size_t)b * NC * HW + (size_t)h * 256 + col;
    for (int i = imin; i <= imax; i++) {
        acc -= __bfloat162float(z[base + (size_t)i * (HW - 2)]);
    }
    temp[idx] = acc * alpha[col];
}

// ---------------- K4: out = x_pre + delta * temp_gathered * PhiL_pv (x4 vectorized) ----------------
__global__ void k4_out(const float* __restrict__ x_pre, const bf16* __restrict__ philpv,
                       const float* __restrict__ temp, const float* __restrict__ delta,
                       float* __restrict__ out)
{
    int idx4 = blockIdx.x * 256 + threadIdx.x;   // quad index; exact grid
    int wq4 = idx4 & 63;
    int rest = idx4 >> 6;
    int h = rest & 255; rest >>= 8;
    int i = rest % NC;
    int b = rest / NC;
    int w = wq4 * 4;
    int col = w + 2 * i;
    const float* trow = temp + ((size_t)(b * 256 + h)) * COLW + col;
    float t0 = trow[0], t1 = trow[1], t2 = trow[2], t3 = trow[3];
    size_t off = ((size_t)(b * NC + i)) * HW + (size_t)(h * 256 + w);
    uint2 pu = *reinterpret_cast<const uint2*>(philpv + off);
    float4 xp = *reinterpret_cast<const float4*>(x_pre + off);
    float d = delta[0];
    float4 o4;
    o4.x = fmaf(d * t0, bflo(pu.x), xp.x);
    o4.y = fmaf(d * t1, bfhi(pu.x), xp.y);
    o4.z = fmaf(d * t2, bflo(pu.y), xp.z);
    o4.w = fmaf(d * t3, bfhi(pu.y), xp.w);
    *reinterpret_cast<float4*>(out + off) = o4;
}

// ---------------- launch ----------------
extern "C" void kernel_launch(void* const* d_in, const int* in_sizes, int n_in,
                              void* d_out, int out_size, void* d_ws, size_t ws_size,
                              hipStream_t stream)
{
    const float* y     = (const float*)d_in[0];
    const float* Phi   = (const float*)d_in[1];
    const float* x_pre = (const float*)d_in[2];
    const float* delta = (const float*)d_in[3];
    const float* mm_w1 = (const float*)d_in[4];
    const float* mm_b1 = (const float*)d_in[5];
    const float* mm_w2 = (const float*)d_in[6];
    const float* mm_b2 = (const float*)d_in[7];
    const float* mm_dw = (const float*)d_in[8];
    const float* mm_db = (const float*)d_in[9];
    const float* pv_w1 = (const float*)d_in[10];
    const float* pv_b1 = (const float*)d_in[11];
    const float* pv_w2 = (const float*)d_in[12];
    const float* pv_b2 = (const float*)d_in[13];
    const float* pv_dw = (const float*)d_in[14];
    const float* pv_db = (const float*)d_in[15];
    float* out = (float*)d_out;

    char* ws = (char*)d_ws;
    const size_t A = (size_t)BATCH * NC * HW * 4;   // 117,440,512 B
    unsigned int* hdr    = (unsigned int*)ws;
    unsigned int* t_pk   = (unsigned int*)(ws + HDR_BYTES);
    unsigned int* m1_pk  = (unsigned int*)(ws + HDR_BYTES + A);
    bf16*         zz     = (bf16*)(ws + HDR_BYTES + 2 * A);
    bf16*         philpv = (bf16*)(ws + HDR_BYTES + 2 * A + A / 2);
    float*        temp   = (float*)(ws + HDR_BYTES + 3 * A);
    const float*  alpha  = (const float*)(ws + 2352 * 4);

    k0_prep<<<1, 256, 0, stream>>>(mm_w1, pv_w1, mm_w2, pv_w2,
                                   mm_b1, pv_b1, mm_b2, pv_b2,
                                   mm_dw, pv_dw, mm_db, pv_db, hdr);
    k1_conv1x1<<<1024, 256, 0, stream>>>(Phi, hdr, t_pk, m1_pk);
    k2_attn<<<BATCH * NC * 16, 256, 0, stream>>>(t_pk, m1_pk, x_pre, hdr, zz, philpv);
    k3_aop<<<(BATCH * ROWW * COLW + 255) / 256, 256, 0, stream>>>(y, zz, alpha, temp);
    k4_out<<<(BATCH * NC * HW / 4) / 256, 256, 0, stream>>>(x_pre, philpv, temp, delta, out);
}